// Round 4
// baseline (6601.869 us; speedup 1.0000x reference)
//
#include <hip/hip_runtime.h>

#define N_ATOM 100000
#define M_NBR  12
#define NF     41
#define AF     64
#define NC     3
#define N0C    100
#define APC    1000
#define HF     128
#define HID    64
#define EPS    1e-5f

typedef unsigned short u16;

__device__ __forceinline__ float b2f(u16 u) {
    return __uint_as_float(((unsigned int)u) << 16);
}
__device__ __forceinline__ u16 f2b(float f) {
    unsigned int x = __float_as_uint(f);
    unsigned int r = x + 0x7fffu + ((x >> 16) & 1u);
    return (u16)(r >> 16);
}
// dtype-flexible load: f==1 -> buffer is float32, else bf16
__device__ __forceinline__ float ldf(const void* p, long i, int f) {
    if (f) return ((const float*)p)[i];
    return b2f(((const u16*)p)[i]);
}
__device__ __forceinline__ float spf(float x) {           // softplus, stable
    return fmaxf(x, 0.0f) + log1pf(expf(-fabsf(x)));
}
__device__ __forceinline__ float sigf(float x) {
    return 1.0f / (1.0f + expf(-x));
}

// ---- dtype probe: decode first 8192 u16 of nbr_fea as bf16; count implausible ----
__global__ void k_probe(const u16* __restrict__ nf, int* __restrict__ flag) {
    int t = threadIdx.x;  // 256
    int bad = 0;
    for (int i = t; i < 8192; i += 256) {
        u16 u = nf[i];
        float v = b2f(u);
        float a = fabsf(v);
        if (!(a <= 1024.0f) || (((u & 0x7fffu) != 0) && a < 1e-10f)) bad++;
    }
    __shared__ int cnt;
    if (t == 0) cnt = 0;
    __syncthreads();
    atomicAdd(&cnt, bad);
    __syncthreads();
    if (t == 0) flag[0] = (cnt > 800) ? 1 : 0;
}

// ---- stage layer params into fp32 ws buffers (dtype-agnostic downstream) ----
__global__ void k_stage(const void* __restrict__ W, long Woff,
                        const void* __restrict__ b, long boff,
                        const void* __restrict__ g1, const void* __restrict__ b1,
                        const void* __restrict__ g2, const void* __restrict__ b2, long L,
                        float* __restrict__ Wst, float* __restrict__ bst,
                        float* __restrict__ bn1s, float* __restrict__ bn2s,
                        const int* __restrict__ flag) {
    int f = flag[0];
    long i = (long)blockIdx.x * 256 + threadIdx.x;
    const long NW_ = (long)(2 * AF + NF) * 128;  // 21632
    if (i < NW_) {
        Wst[i] = ldf(W, Woff + i, f);
    } else if (i < NW_ + 128) {
        long c = i - NW_;
        bst[c] = ldf(b, boff + c, f);
        bn1s[c] = ldf(g1, L * 128 + c, f);
        bn1s[128 + c] = ldf(b1, L * 128 + c, f);
        if (c < 64) {
            bn2s[c] = ldf(g2, L * 64 + c, f);
            bn2s[64 + c] = ldf(b2, L * 64 + c, f);
        }
    }
}

// ---- atom_fea = embedding[atom_num], stored bf16 in ws ----
__global__ void k_embed(const int* __restrict__ atom_num, const void* __restrict__ emb,
                        u16* __restrict__ af, const int* __restrict__ flag) {
    int f = flag[0];
    int i = blockIdx.x * 256 + threadIdx.x;
    if (i < N_ATOM * AF) {
        int n = i >> 6, c = i & 63;
        af[i] = f2b(ldf(emb, (long)atom_num[n] * AF + c, f));
    }
}

// ---- An = af @ W[64:128] (fp32 staged W), stored bf16. one wave/atom, 2 ch/lane ----
__global__ __launch_bounds__(256) void k_an(const u16* __restrict__ af,
                       const float* __restrict__ Wst, u16* __restrict__ An) {
    int wv = threadIdx.x >> 6;
    int lane = threadIdx.x & 63;
    int n = blockIdx.x * 4 + wv;
    float afv = b2f(af[n * AF + lane]);
    float a0 = 0.f, a1 = 0.f;
    for (int k = 0; k < AF; ++k) {
        float a = __shfl(afv, k, 64);
        a0 = fmaf(a, Wst[(AF + k) * 128 + lane], a0);
        a1 = fmaf(a, Wst[(AF + k) * 128 + 64 + lane], a1);
    }
    An[(long)n * 128 + lane] = f2b(a0);
    An[(long)n * 128 + 64 + lane] = f2b(a1);
}

// ---- conv sweep. As recomputed per atom from staged fp32 W.
// APPLY=false -> bn1 stats; true -> apply bn1 + gate + summed + bn2 stats.
// RECOMP_AN: low-ws path recomputes An[j] per edge instead of reading it.
template<bool APPLY, bool RECOMP_AN>
__global__ __launch_bounds__(256) void k_conv(const void* __restrict__ nbr_fea,
                       const int* __restrict__ nbr_idx,
                       const u16* __restrict__ af, const u16* __restrict__ An,
                       const float* __restrict__ Wst, const float* __restrict__ bst,
                       const float* __restrict__ st1,   // [0:128]=scale [128:256]=shift
                       u16* __restrict__ summed,
                       float* __restrict__ statsOut,
                       const int* __restrict__ flag) {
    int f = flag[0];
    int lane = threadIdx.x & 63;
    int wv = threadIdx.x >> 6;
    int gwave = blockIdx.x * 4 + wv;
    int NW = gridDim.x * 4;
    // register-resident W_edge columns {lane, lane+64}; rows 128..168
    float w0[NF], w1[NF];
    #pragma unroll
    for (int k = 0; k < NF; ++k) {
        w0[k] = Wst[(128 + k) * 128 + lane];
        w1[k] = Wst[(128 + k) * 128 + 64 + lane];
    }
    float b0 = bst[lane];
    float b1 = bst[64 + lane];
    float s0 = 0.f, t0 = 0.f, s1 = 0.f, t1 = 0.f;
    if (APPLY) {
        s0 = st1[lane];        s1 = st1[lane + 64];
        t0 = st1[128 + lane];  t1 = st1[192 + lane];
    }
    float sum0 = 0.f, ssq0 = 0.f, sum1 = 0.f, ssq1 = 0.f;
    for (int n = gwave; n < N_ATOM; n += NW) {
        // As = af[n] @ W[0:64] + b
        float afv = b2f(af[n * AF + lane]);
        float as0 = b0, as1 = b1;
        for (int k = 0; k < AF; ++k) {
            float a = __shfl(afv, k, 64);
            as0 = fmaf(a, Wst[k * 128 + lane], as0);
            as1 = fmaf(a, Wst[k * 128 + 64 + lane], as1);
        }
        float asum = 0.f;
        for (int m = 0; m < M_NBR; ++m) {
            long r = (long)n * M_NBR + m;
            int j = nbr_idx[r];
            float nv = (lane < NF) ? ldf(nbr_fea, r * NF + lane, f) : 0.f;
            float e0 = as0, e1 = as1;
            #pragma unroll
            for (int k = 0; k < NF; ++k) {
                float v = __shfl(nv, k, 64);
                e0 = fmaf(v, w0[k], e0);
                e1 = fmaf(v, w1[k], e1);
            }
            float g0, g1;
            if (RECOMP_AN) {
                float aj = b2f(af[(long)j * AF + lane]);
                float an0 = 0.f, an1 = 0.f;
                for (int k = 0; k < AF; ++k) {
                    float a = __shfl(aj, k, 64);
                    an0 = fmaf(a, Wst[(AF + k) * 128 + lane], an0);
                    an1 = fmaf(a, Wst[(AF + k) * 128 + 64 + lane], an1);
                }
                g0 = e0 + an0; g1 = e1 + an1;
            } else {
                g0 = e0 + b2f(An[(long)j * 128 + lane]);
                g1 = e1 + b2f(An[(long)j * 128 + 64 + lane]);
            }
            if (APPLY) {
                float ft = sigf(fmaf(g0, s0, t0));
                float cc = spf(fmaf(g1, s1, t1));
                asum += ft * cc;
            } else {
                sum0 += g0; ssq0 += g0 * g0;
                sum1 += g1; ssq1 += g1 * g1;
            }
        }
        if (APPLY) {
            summed[(long)n * 64 + lane] = f2b(asum);
            sum0 += asum; ssq0 += asum * asum;
        }
    }
    __shared__ float red[256];
    if (APPLY) {
        if (threadIdx.x < 128) red[threadIdx.x] = 0.f;
        __syncthreads();
        atomicAdd(&red[lane], sum0);
        atomicAdd(&red[64 + lane], ssq0);
        __syncthreads();
        if (threadIdx.x < 128) atomicAdd(&statsOut[threadIdx.x], red[threadIdx.x]);
    } else {
        red[threadIdx.x] = 0.f;
        __syncthreads();
        atomicAdd(&red[lane], sum0);
        atomicAdd(&red[64 + lane], sum1);
        atomicAdd(&red[128 + lane], ssq0);
        atomicAdd(&red[192 + lane], ssq1);
        __syncthreads();
        atomicAdd(&statsOut[threadIdx.x], red[threadIdx.x]);
    }
}

__global__ void k_bn1(const float* __restrict__ stats, const float* __restrict__ bn1s,
                      float* __restrict__ st) {
    int c = threadIdx.x;  // 128
    float cnt = (float)N_ATOM * (float)M_NBR;
    float mu = stats[c] / cnt;
    float var = fmaxf(stats[128 + c] / cnt - mu * mu, 0.0f);
    float s = bn1s[c] * rsqrtf(var + EPS);
    st[c] = s;
    st[128 + c] = bn1s[128 + c] - mu * s;
}

__global__ void k_bn2(const float* __restrict__ stats, const float* __restrict__ bn2s,
                      float* __restrict__ st) {
    int c = threadIdx.x;  // 64
    float cnt = (float)N_ATOM;
    float mu = stats[c] / cnt;
    float var = fmaxf(stats[64 + c] / cnt - mu * mu, 0.0f);
    float s = bn2s[c] * rsqrtf(var + EPS);
    st[c] = s;
    st[64 + c] = bn2s[64 + c] - mu * s;
}

__global__ void k_update(u16* __restrict__ af, const u16* __restrict__ summed,
                         const float* __restrict__ st2) {
    int i = blockIdx.x * 256 + threadIdx.x;
    if (i < N_ATOM * 64) {
        int c = i & 63;
        float v = fmaf(b2f(summed[i]), st2[c], st2[64 + c]);
        af[i] = f2b(spf(b2f(af[i]) + v));
    }
}

__global__ void k_pool(const u16* __restrict__ af, const int* __restrict__ cidx,
                       float* __restrict__ crysp) {
    int b = blockIdx.x;
    int ch = threadIdx.x & 63;
    int part = threadIdx.x >> 6;
    float acc = 0.f;
    for (int k = part; k < APC; k += 4) {
        int a = cidx[b * APC + k];
        acc += b2f(af[(long)a * 64 + ch]);
    }
    __shared__ float red[256];
    red[threadIdx.x] = acc;
    __syncthreads();
    if (part == 0) {
        float s = red[ch] + red[64 + ch] + red[128 + ch] + red[192 + ch];
        crysp[b * 64 + ch] = spf(s * (1.0f / APC));
    }
}

__global__ void k_head(const float* __restrict__ crysp, const void* __restrict__ Wfc,
                       const void* __restrict__ bfc, const void* __restrict__ Wout,
                       const void* __restrict__ bout, void* __restrict__ outv,
                       const int* __restrict__ flag) {
    int f = flag[0];
    int b = blockIdx.x;
    int t = threadIdx.x;  // 128
    __shared__ float cr[64];
    __shared__ float h[HF];
    if (t < 64) cr[t] = crysp[b * 64 + t];
    __syncthreads();
    float acc = ldf(bfc, t, f);
    for (int k = 0; k < 64; ++k) acc = fmaf(cr[k], ldf(Wfc, (long)k * HF + t, f), acc);
    h[t] = spf(acc);
    __syncthreads();
    if (t < HID) {
        float o = ldf(bout, t, f);
        for (int k = 0; k < HF; ++k) o = fmaf(h[k], ldf(Wout, (long)k * HID + t, f), o);
        if (f) ((float*)outv)[b * HID + t] = o;
        else   ((u16*)outv)[b * HID + t] = f2b(o);
    }
}

extern "C" void kernel_launch(void* const* d_in, const int* in_sizes, int n_in,
                              void* d_out, int out_size, void* d_ws, size_t ws_size,
                              hipStream_t stream) {
    const int* atom_num = (const int*)d_in[0];
    const void* nbr_fea = d_in[1];
    const int* nbr_idx  = (const int*)d_in[2];
    const int* cidx     = (const int*)d_in[3];
    const void* emb     = d_in[4];
    const void* W_full  = d_in[5];
    const void* b_full  = d_in[6];
    const void* bn1_g   = d_in[7];
    const void* bn1_b   = d_in[8];
    const void* bn2_g   = d_in[9];
    const void* bn2_b   = d_in[10];
    const void* W_fc    = d_in[11];
    const void* b_fc    = d_in[12];
    const void* W_out   = d_in[13];
    const void* b_out   = d_in[14];

    // ---- ws layout: control + staging first, big arrays after ----
    char* wsb = (char*)d_ws;
    int*   flag   = (int*)wsb;                          // 16 B
    float* stats1 = (float*)(wsb + 16);                 // 256
    float* st1    = stats1 + 256;                       // 256
    float* stats2 = st1 + 256;                          // 128
    float* st2    = stats2 + 128;                       // 128
    float* crysp  = st2 + 128;                          // 6400
    float* Wst    = crysp + 6400;                       // 21632
    float* bst    = Wst + 21632;                        // 128
    float* bn1s   = bst + 128;                          // 256
    float* bn2s   = bn1s + 256;                         // 128
    u16*   af     = (u16*)(bn2s + 128);                 // N*64 bf16 = 12.8 MB
    u16*   summed = af + (long)N_ATOM * 64;             // N*64 bf16 = 12.8 MB
    u16*   An     = summed + (long)N_ATOM * 64;         // N*128 bf16 = 25.6 MB (fast path)
    size_t need_fast = (size_t)((char*)(An + (long)N_ATOM * 128) - wsb);
    bool fast = ws_size >= need_fast;

    k_probe<<<1, 256, 0, stream>>>((const u16*)nbr_fea, flag);
    k_embed<<<(N_ATOM * 64 + 255) / 256, 256, 0, stream>>>(atom_num, emb, af, flag);

    const long WROWS = (long)(2 * AF + NF) * 128;  // 21632
    for (int L = 0; L < NC; ++L) {
        hipMemsetAsync(stats1, 0, 768 * sizeof(float), stream);
        k_stage<<<(int)((WROWS + 128 + 255) / 256), 256, 0, stream>>>(
            W_full, (long)L * WROWS, b_full, (long)L * 128,
            bn1_g, bn1_b, bn2_g, bn2_b, (long)L,
            Wst, bst, bn1s, bn2s, flag);
        if (fast) {
            k_an<<<N_ATOM / 4, 256, 0, stream>>>(af, Wst, An);
            k_conv<false, false><<<2500, 256, 0, stream>>>(nbr_fea, nbr_idx, af, An,
                                                           Wst, bst, nullptr, nullptr, stats1, flag);
        } else {
            k_conv<false, true><<<2500, 256, 0, stream>>>(nbr_fea, nbr_idx, af, nullptr,
                                                          Wst, bst, nullptr, nullptr, stats1, flag);
        }
        k_bn1<<<1, 128, 0, stream>>>(stats1, bn1s, st1);
        if (fast) {
            k_conv<true, false><<<2500, 256, 0, stream>>>(nbr_fea, nbr_idx, af, An,
                                                          Wst, bst, st1, summed, stats2, flag);
        } else {
            k_conv<true, true><<<2500, 256, 0, stream>>>(nbr_fea, nbr_idx, af, nullptr,
                                                         Wst, bst, st1, summed, stats2, flag);
        }
        k_bn2<<<1, 64, 0, stream>>>(stats2, bn2s, st2);
        k_update<<<(N_ATOM * 64 + 255) / 256, 256, 0, stream>>>(af, summed, st2);
    }
    k_pool<<<N0C, 256, 0, stream>>>(af, cidx, crysp);
    k_head<<<N0C, HF, 0, stream>>>(crysp, W_fc, b_fc, W_out, b_out, d_out, flag);
}